// Round 1
// baseline (3749.517 us; speedup 1.0000x reference)
//
#include <hip/hip_runtime.h>
#include <cstdint>
#include <cfloat>

// Problem constants (fixed dataset: B=512, D=128, N=1M, E=50, K=100)
#define NQ     512
#define DIM    128
#define NCAND  1048576
#define TOPK   150      // adjusted k = K + E
#define KOUT   100
#define NEXCL  50
#define STATE_STRIDE 160  // per-query stride in state arrays (alignment)
#define POOL   2048       // merge pool capacity (power of 2)

// ---------------------------------------------------------------------------
// Kernel A: fp32 GEMM  S[q][c] = dot(Q[q], Cand[cand_base+c])  for a chunk.
// Block tile 64 queries x 64 candidates, 256 threads, 4x4 microtile.
// LDS: full K=128 staged once; XOR swizzle (col4 ^= (row>>2)&7) keeps the
// b128 fragment reads at <=2-way bank aliasing (free per guide G4).
// ---------------------------------------------------------------------------
__global__ __launch_bounds__(256) void score_gemm(
    const float* __restrict__ q,       // [NQ][DIM]
    const float* __restrict__ cand,    // [NCAND][DIM]
    float* __restrict__ S,             // [NQ][C] chunk scores
    int cand_base, int C)
{
  __shared__ float As[64 * 128];
  __shared__ float Bs[64 * 128];
  const int t  = threadIdx.x;
  const int c0 = blockIdx.x * 64;   // candidate tile base within chunk
  const int q0 = blockIdx.y * 64;   // query tile base

  // Stage both tiles: idx = iter*256+t; row = idx>>5 (0..63), c4 = idx&31.
  // Wave covers 2 rows x 32 float4 contiguous -> coalesced global reads.
  for (int iter = 0; iter < 8; ++iter) {
    int idx = iter * 256 + t;
    int row = idx >> 5;
    int c4  = idx & 31;
    int sw  = c4 ^ ((row >> 2) & 7);          // XOR swizzle
    float4 av = *(const float4*)(q + (size_t)(q0 + row) * DIM + c4 * 4);
    *(float4*)(As + row * 128 + sw * 4) = av;
    float4 bv = *(const float4*)(cand + (size_t)(cand_base + c0 + row) * DIM + c4 * 4);
    *(float4*)(Bs + row * 128 + sw * 4) = bv;
  }
  __syncthreads();

  const int tm = t >> 4;    // 0..15 -> query rows 4*tm..+3
  const int tn = t & 15;    // 0..15 -> cand cols 4*tn..+3
  float acc[4][4];
#pragma unroll
  for (int m = 0; m < 4; ++m)
#pragma unroll
    for (int n = 0; n < 4; ++n) acc[m][n] = 0.0f;

#pragma unroll 4
  for (int k4 = 0; k4 < 32; ++k4) {
    float4 a[4], b[4];
#pragma unroll
    for (int m = 0; m < 4; ++m)
      a[m] = *(const float4*)(As + (4 * tm + m) * 128 + ((k4 ^ (tm & 7)) * 4));
#pragma unroll
    for (int n = 0; n < 4; ++n)
      b[n] = *(const float4*)(Bs + (4 * tn + n) * 128 + ((k4 ^ (tn & 7)) * 4));
#pragma unroll
    for (int m = 0; m < 4; ++m)
#pragma unroll
      for (int n = 0; n < 4; ++n) {
        acc[m][n] += a[m].x * b[n].x;
        acc[m][n] += a[m].y * b[n].y;
        acc[m][n] += a[m].z * b[n].z;
        acc[m][n] += a[m].w * b[n].w;
      }
  }

#pragma unroll
  for (int m = 0; m < 4; ++m) {
    float4 v = make_float4(acc[m][0], acc[m][1], acc[m][2], acc[m][3]);
    *(float4*)(S + (size_t)(q0 + 4 * tm + m) * C + c0 + 4 * tn) = v;
  }
}

// ---------------------------------------------------------------------------
// Bitonic sort of POOL entries, descending by (score desc, id asc).
// ---------------------------------------------------------------------------
__device__ inline void bitonic_sort_desc(float* ps, int* pi, int t)
{
  for (int size = 2; size <= POOL; size <<= 1) {
    for (int stride = size >> 1; stride > 0; stride >>= 1) {
      __syncthreads();
      for (int i = t; i < POOL / 2; i += 256) {
        int idx = 2 * i - (i & (stride - 1));
        int j   = idx + stride;
        bool desc = ((idx & size) == 0);
        float s1 = ps[idx], s2 = ps[j];
        int   i1 = pi[idx], i2 = pi[j];
        bool jBetter = (s2 > s1) || (s2 == s1 && i2 < i1);
        if (jBetter == desc) {
          ps[idx] = s2; ps[j] = s1;
          pi[idx] = i2; pi[j] = i1;
        }
      }
    }
  }
  __syncthreads();
}

// ---------------------------------------------------------------------------
// Kernel B: per-query merge of chunk scores into running top-150 state.
// Pool-with-threshold: append survivors, bitonic-prune when near capacity.
// ---------------------------------------------------------------------------
__global__ __launch_bounds__(256) void topk_merge(
    const float* __restrict__ S,        // [NQ][C]
    float* __restrict__ st_s,           // [NQ][STATE_STRIDE]
    int*   __restrict__ st_i,           // [NQ][STATE_STRIDE]
    int cand_base, int C, int first)
{
  __shared__ float ps[POOL];
  __shared__ int   pi[POOL];
  __shared__ int   cnt;
  __shared__ float thr;
  const int b = blockIdx.x;
  const int t = threadIdx.x;

  if (t == 0) {
    cnt = first ? 0 : TOPK;
    thr = first ? -FLT_MAX : st_s[(size_t)b * STATE_STRIDE + TOPK - 1];
  }
  if (!first && t < TOPK) {
    ps[t] = st_s[(size_t)b * STATE_STRIDE + t];
    pi[t] = st_i[(size_t)b * STATE_STRIDE + t];
  }
  __syncthreads();

  const float4* row = (const float4*)(S + (size_t)b * C);
  const int nIter = C >> 10;           // 1024 candidates per iteration
  for (int it = 0; it < nIter; ++it) {
    if (cnt + 1024 > POOL) {           // uniform: cnt stable since last barrier
      int c = cnt;
      for (int i = t; i < POOL; i += 256)
        if (i >= c) { ps[i] = -FLT_MAX; pi[i] = 0x7fffffff; }
      __syncthreads();
      bitonic_sort_desc(ps, pi, t);
      if (t == 0) { cnt = (c < TOPK) ? c : TOPK; thr = ps[TOPK - 1]; }
      __syncthreads();
    }
    float4 v = row[it * 256 + t];
    int base_id = cand_base + it * 1024 + t * 4;
    float sv[4] = {v.x, v.y, v.z, v.w};
#pragma unroll
    for (int jj = 0; jj < 4; ++jj) {
      if (sv[jj] > thr) {
        int p = atomicAdd(&cnt, 1);
        ps[p] = sv[jj];
        pi[p] = base_id + jj;
      }
    }
    __syncthreads();
  }

  // Final prune + write back sorted top-150 state.
  {
    int c = cnt;
    for (int i = t; i < POOL; i += 256)
      if (i >= c) { ps[i] = -FLT_MAX; pi[i] = 0x7fffffff; }
    __syncthreads();
    bitonic_sort_desc(ps, pi, t);
  }
  if (t < TOPK) {
    st_s[(size_t)b * STATE_STRIDE + t] = ps[t];
    st_i[(size_t)b * STATE_STRIDE + t] = pi[t];
  }
}

// ---------------------------------------------------------------------------
// Kernel C: apply exclusions, stable-compact first 100 kept entries, write
// scores (float) then ids (as float; exact below 2^24) to d_out.
// ---------------------------------------------------------------------------
__global__ __launch_bounds__(256) void finalize(
    const float* __restrict__ st_s,
    const int*   __restrict__ st_i,
    const int*   __restrict__ excl,     // [NQ][NEXCL]
    float* __restrict__ out)            // [NQ*KOUT scores][NQ*KOUT ids]
{
  const int b = blockIdx.x;
  const int t = threadIdx.x;
  __shared__ int ex[NEXCL];
  __shared__ unsigned char keep[TOPK];
  __shared__ short pos[TOPK];

  if (t < NEXCL) ex[t] = excl[(size_t)b * NEXCL + t];
  __syncthreads();
  if (t < TOPK) {
    int id = st_i[(size_t)b * STATE_STRIDE + t];
    bool k = true;
#pragma unroll
    for (int j = 0; j < NEXCL; ++j) k = k && (id != ex[j]);
    keep[t] = (unsigned char)k;
  }
  __syncthreads();
  if (t == 0) {
    int p = 0;
    for (int i = 0; i < TOPK; ++i) {
      pos[i] = (keep[i] && p < KOUT) ? (short)p : (short)-1;
      if (keep[i]) ++p;
    }
  }
  __syncthreads();
  if (t < TOPK) {
    int p = pos[t];
    if (p >= 0) {
      out[(size_t)b * KOUT + p] = st_s[(size_t)b * STATE_STRIDE + t];
      out[(size_t)NQ * KOUT + (size_t)b * KOUT + p] =
          (float)st_i[(size_t)b * STATE_STRIDE + t];
    }
  }
}

// ---------------------------------------------------------------------------
extern "C" void kernel_launch(void* const* d_in, const int* in_sizes, int n_in,
                              void* d_out, int out_size, void* d_ws, size_t ws_size,
                              hipStream_t stream)
{
  (void)in_sizes; (void)n_in; (void)out_size;
  const float* q    = (const float*)d_in[0];
  const float* cand = (const float*)d_in[1];
  // d_in[2] = identifiers (arange(N)) -> candidate index used directly
  const int*   excl = (const int*)d_in[3];
  float* out = (float*)d_out;

  // Workspace layout: state scores | state ids | chunk score matrix S
  const size_t state_one = (size_t)NQ * STATE_STRIDE * 4;
  float* st_s = (float*)d_ws;
  int*   st_i = (int*)((char*)d_ws + state_one);
  float* S    = (float*)((char*)d_ws + 2 * state_one);

  // Pick the largest chunk C (candidates per pass) that fits in ws.
  long long avail = (long long)ws_size - 2 * (long long)state_one;
  int C = 262144;
  while (C > 1024 && (long long)C * NQ * 4 > avail) C >>= 1;

  const int nchunks = NCAND / C;
  for (int j = 0; j < nchunks; ++j) {
    dim3 grid(C / 64, NQ / 64);
    score_gemm<<<grid, 256, 0, stream>>>(q, cand, S, j * C, C);
    topk_merge<<<NQ, 256, 0, stream>>>(S, st_s, st_i, j * C, C, j == 0);
  }
  finalize<<<NQ, 256, 0, stream>>>(st_s, st_i, excl, out);
}